// Round 15
// baseline (96.048 us; speedup 1.0000x reference)
//
#include <hip/hip_runtime.h>
#include <hip/hip_bf16.h>
#include <stdint.h>

typedef __attribute__((ext_vector_type(8))) short bf16x8;
typedef __attribute__((ext_vector_type(4))) float f32x4;
typedef __attribute__((ext_vector_type(4))) unsigned short u16x4;
typedef unsigned short u16;

#define D_MODEL 1024
#define DK 128
#define BATCH 8
#define SEQ 2048
#define NROWS (BATCH * SEQ) /* 16384 */
#define NSPLIT 4
#define KVPB 512  /* KV rows per block */
#define NIT 16    /* KVPB / 32 */

static __device__ __forceinline__ void gl_lds16(const void* g, void* l) {
  __builtin_amdgcn_global_load_lds((const __attribute__((address_space(1))) void*)g,
                                   (__attribute__((address_space(3))) void*)l, 16, 0, 0);
}

static __device__ __forceinline__ u16 f2b(float f) {
  __hip_bfloat16 h = __float2bfloat16(f);
  return *reinterpret_cast<u16*>(&h);
}

static __device__ __forceinline__ uint32_t cvtpk(float lo, float hi) {
  uint32_t r;
  asm("v_cvt_pk_bf16_f32 %0, %1, %2" : "=v"(r) : "v"(lo), "v"(hi));
  return r;
}

static __device__ __forceinline__ float exp2hw(float x) {
  float r;
  asm("v_exp_f32 %0, %1" : "=v"(r) : "v"(x));
  return r;
}

// ---------------- Kernel 0: W -> bf16, BK=64-tile-major pre-swizzled layout -----------
// wt3[kt][np][slot] : kt = k>>6 (16 K-tiles), np = w*128+n (0..383),
// slot = ((k>>3)&7) ^ ((np>>1)&7)  (granule-XOR PRE-APPLIED), elem = k&7.
// Every MFMA B-fragment (lane, kk, g, ni) is a CONTIGUOUS 16 B at
// wt3 + kt*49152 + np*128 + slot*16 -> direct per-lane global load, no LDS needed.
__global__ __launch_bounds__(256) void wcvt(const float* __restrict__ wq,
                                            const float* __restrict__ wk,
                                            const float* __restrict__ wv,
                                            u16* __restrict__ wt3) {
  const int idx = blockIdx.x * 256 + threadIdx.x;  // exactly 393216
  int w = idx >> 17, rr = idx & 131071, k = rr >> 7, n = rr & 127;
  const float* W = (w == 0) ? wq : ((w == 1) ? wk : wv);
  int np = w * 128 + n;
  int kt = k >> 6;
  int slot = ((k >> 3) & 7) ^ ((np >> 1) & 7);
  size_t dst = ((size_t)kt * 3072 + np * 8 + slot) * 8 + (k & 7);
  wt3[dst] = f2b(W[k * DK + n]);
}

// ---------------- Kernel 1: fused cvt+GEMM v9: NO LDS, NO BARRIERS --------------------
// gl_lds staging is capped ~6.5 TB/s chip-wide for non-L2-resident sources (R6-R14:
// every variant 6-7.5 TB/s staged). v9 bypasses it: each wave streams A (f32, linear,
// cvtpk in-reg) and B (pre-swizzled wt3, per-lane contiguous 16 B fragments) DIRECTLY
// from global into MFMA operands. No LDS, no barriers, no waitcnt — independent waves
// with deep per-wave load queues (the property that makes attn fast). 256 blocks x
// 512 thr (8 waves = 2Mx4N); A-tile (16 KB/kt) is read 4x per block but L1-resident.
// Col 0-127 -> Q (pre-scaled log2e/sqrt(128)), 128-255 -> K, 256-383 -> V^T sigma-perm.
__global__ __launch_bounds__(512, 1) void qkv_gemm(const float* __restrict__ x,
                                                   const u16* __restrict__ wt3,
                                                   u16* __restrict__ qb,
                                                   u16* __restrict__ kb,
                                                   u16* __restrict__ vt) {
  const int tid = threadIdx.x;        // 0..511
  const int lane = tid & 63;
  const int w = tid >> 6;             // 0..7
  const int g = lane >> 4;            // 0..3
  const int l15 = lane & 15;
  const int mt = blockIdx.x;          // 0..255 (64-row panel); 1 block/CU
  const int wm = w >> 2, wn = w & 3;  // wave owns rows 32*wm..+31, cols 96*wn..+95

  const char* aB = (const char*)x + (size_t)mt * 64 * 4096;  // f32 row stride 4096 B
  const char* bB = (const char*)wt3;

  f32x4 acc[2][6];
#pragma unroll
  for (int i = 0; i < 2; ++i)
#pragma unroll
    for (int jj = 0; jj < 6; ++jj) acc[i][jj] = (f32x4){0.f, 0.f, 0.f, 0.f};

  // Per-lane base pointers (loop-invariant)
  const char* aRow0 = aB + (size_t)(wm * 32 + 0 * 16 + l15) * 4096;
  const char* aRow1 = aB + (size_t)(wm * 32 + 1 * 16 + l15) * 4096;

#pragma unroll 2
  for (int kt = 0; kt < 16; ++kt) {
#pragma unroll
    for (int kk = 0; kk < 2; ++kk) {
      // A fragments: rows wm*32+mi*16+l15, cols kk*32+g*8..+7 (32 B contiguous f32)
      bf16x8 af[2];
#pragma unroll
      for (int mi = 0; mi < 2; ++mi) {
        const char* ap = (mi ? aRow1 : aRow0) + kt * 256 + kk * 128 + g * 32;
        f32x4 lo = *(const f32x4*)ap;
        f32x4 hi = *(const f32x4*)(ap + 16);
        union { uint32_t u[4]; bf16x8 v; } tt;
        tt.u[0] = cvtpk(lo[0], lo[1]);
        tt.u[1] = cvtpk(lo[2], lo[3]);
        tt.u[2] = cvtpk(hi[0], hi[1]);
        tt.u[3] = cvtpk(hi[2], hi[3]);
        af[mi] = tt.v;
      }
      // B fragments: direct per-lane contiguous 16 B from pre-swizzled wt3
      bf16x8 bfr[6];
#pragma unroll
      for (int ni = 0; ni < 6; ++ni) {
        int np = wn * 96 + ni * 16 + l15;
        int slot = (kk * 4 + g) ^ ((np >> 1) & 7);
        bfr[ni] = *(const bf16x8*)(bB + (size_t)kt * 49152 + np * 128 + slot * 16);
      }
      __builtin_amdgcn_s_setprio(1);
#pragma unroll
      for (int mi = 0; mi < 2; ++mi)
#pragma unroll
        for (int ni = 0; ni < 6; ++ni)
          acc[mi][ni] = __builtin_amdgcn_mfma_f32_16x16x32_bf16(af[mi], bfr[ni], acc[mi][ni], 0, 0, 0);
      __builtin_amdgcn_s_setprio(0);
    }
  }

  // qscale = (1/sqrt(128)) * log2(e): softmax done as exp2 with no max subtraction
  const float qscale = 0.12751743f;
#pragma unroll
  for (int mi = 0; mi < 2; ++mi) {
#pragma unroll
    for (int ni = 0; ni < 6; ++ni) {
      int mbase = mt * 64 + wm * 32 + mi * 16 + g * 4;
      int np = wn * 96 + ni * 16 + l15;
      int ntd = np >> 7, n = np & 127;
      if (ntd == 2) {
        int b = mbase >> 11, s = mbase & 2047;
        // sigma-permute: 4-granule a within 32-block -> position 2*(a&3) + (a>>2)
        int a = (s >> 2) & 7;
        int sp2 = (s & ~31) | ((((a & 3) << 1) | (a >> 2)) << 2);
        union { u16 u[4]; u16x4 v; } pk;
#pragma unroll
        for (int r2 = 0; r2 < 4; ++r2) pk.u[r2] = f2b(acc[mi][ni][r2]);
        *(u16x4*)((char*)vt + ((size_t)(b * 128 + n) * 2048 + sp2) * 2) = pk.v;
      } else {
        u16* dst = (ntd == 0) ? qb : kb;
        float sc = (ntd == 0) ? qscale : 1.0f;
#pragma unroll
        for (int r2 = 0; r2 < 4; ++r2)
          dst[(size_t)(mbase + r2) * 128 + n] = f2b(acc[mi][ni][r2] * sc);
      }
    }
  }
}

// ---------------- Kernel 2: flash attention partial, 3-buf deep prefetch, 1 barrier ---
// Q pre-scaled bf16 [b][s][128]; K bf16 [b][s][128]; V^T bf16 [b][d][s] sigma-permuted.
__global__ __launch_bounds__(256) void attn(const u16* __restrict__ qb,
                                            const u16* __restrict__ kb,
                                            const u16* __restrict__ vtg,
                                            u16* __restrict__ po,
                                            float* __restrict__ ls) {
  __shared__ char sm[49152] __attribute__((aligned(16)));  // K 3x8K | V 3x8K
  const int tid = threadIdx.x, lane = tid & 63, w = tid >> 6;  // 4 waves
  const int g = lane >> 4, l15 = lane & 15;
  // XCD swizzle: batch b's 64 blocks (4 splits x 16 q-tiles) land on one XCD
  const int id = blockIdx.x;  // 0..511
  const int wgid = ((id & 7) << 6) | (id >> 3);
  const int b = wgid >> 6, sp = (wgid >> 4) & 3, j = wgid & 15;
  const int s0q = j * 128 + w * 32;
  const int kv0 = sp * KVPB;

  const char* qB = (const char*)qb + (size_t)b * SEQ * 256;
  const char* kB = (const char*)kb + (size_t)b * SEQ * 256;
  const char* vB = (const char*)vtg + (size_t)b * 128 * SEQ * 2;

  // Q fragments first (oldest in vmcnt queue): lane holds Q[q=l15][d=kk*32+g*8..+7]
  bf16x8 qf[2][4];
#pragma unroll
  for (int h = 0; h < 2; ++h)
#pragma unroll
    for (int kk = 0; kk < 4; ++kk)
      qf[h][kk] = *(const bf16x8*)(qB + (size_t)(s0q + h * 16 + l15) * 256 + kk * 64 + g * 16);

  f32x4 o[2][8];
#pragma unroll
  for (int h = 0; h < 2; ++h)
#pragma unroll
    for (int i = 0; i < 8; ++i) o[h][i] = (f32x4){0.f, 0.f, 0.f, 0.f};
  float lsum[2] = {0.f, 0.f};

  char* sKb = sm;          // [3][8192] K tile [32 kv][256 B], swizzled
  char* sVb = sm + 24576;  // [3][8192] V^T tile [128 d][64 B], swizzled+sigma-permuted

  auto stage = [&](int bi, int it) {
    char* sK = sKb + bi * 8192;
    char* sV = sVb + bi * 8192;
    int s0 = kv0 + it * 32;
#pragma unroll
    for (int c = 0; c < 2; ++c) {
      int base = c * 4096 + w * 1024;  // wave-uniform LDS dest
      int L = base + lane * 16;
      {
        int row = L >> 8, col = L & 255;
        gl_lds16(kB + (size_t)(s0 + row) * 256 + (col ^ ((row & 7) << 4)), sK + base);
      }
      {
        int rv = L >> 6, cv = L & 63;
        gl_lds16(vB + (size_t)rv * 4096 + (size_t)s0 * 2 + (cv ^ ((rv & 3) << 4)), sV + base);
      }
    }
  };

  stage(0, 0);
  stage(1, 1);
  int cb = 0;
  for (int t = 0; t < NIT; ++t) {
    if (t < NIT - 1) asm volatile("s_waitcnt vmcnt(4)" ::: "memory");
    else asm volatile("s_waitcnt vmcnt(0)" ::: "memory");
    __builtin_amdgcn_s_barrier();
    if (t + 2 < NIT) {
      int sb = cb + 2;
      if (sb >= 3) sb -= 3;
      stage(sb, t + 2);  // writes buf (t+2)%3: disjoint from all live readers
    }
    const char* sK = sKb + cb * 8192;
    const char* sV = sVb + cb * 8192;

    // QK^T (swapped): S^T[kv][q]; A = K fragment (shared across groups), B = Q fragment
    f32x4 st[2][2];
    st[0][0] = (f32x4){0.f, 0.f, 0.f, 0.f}; st[0][1] = st[0][0];
    st[1][0] = st[0][0]; st[1][1] = st[0][0];
    __builtin_amdgcn_s_setprio(1);
#pragma unroll
    for (int sub = 0; sub < 2; ++sub)
#pragma unroll
      for (int kk = 0; kk < 4; ++kk) {
        bf16x8 kf = *(const bf16x8*)(sK + (sub * 16 + l15) * 256 +
                                     ((kk * 64 + g * 16) ^ ((l15 & 7) << 4)));
        st[0][sub] = __builtin_amdgcn_mfma_f32_16x16x32_bf16(kf, qf[0][kk], st[0][sub], 0, 0, 0);
        st[1][sub] = __builtin_amdgcn_mfma_f32_16x16x32_bf16(kf, qf[1][kk], st[1][sub], 0, 0, 0);
      }
    __builtin_amdgcn_s_setprio(0);

    // m=0 softmax: p = exp2(st) (Q pre-scaled by log2e/sqrt(d)); pack in-register.
    // k-slot permutation pi(g*8+j) = g*4+j | 16+g*4+(j-4): B-operand is lane-local.
    union U { uint32_t u[4]; bf16x8 v; } pf[2];
#pragma unroll
    for (int h = 0; h < 2; ++h) {
      float p[8];
#pragma unroll
      for (int sub = 0; sub < 2; ++sub)
#pragma unroll
        for (int r2 = 0; r2 < 4; ++r2) {
          float e = exp2hw(st[h][sub][r2]);
          lsum[h] += e;
          p[sub * 4 + r2] = e;
        }
      pf[h].u[0] = cvtpk(p[0], p[1]);
      pf[h].u[1] = cvtpk(p[2], p[3]);
      pf[h].u[2] = cvtpk(p[4], p[5]);
      pf[h].u[3] = cvtpk(p[6], p[7]);
    }

    // PV: O^T[d][q] += V^T[d][pi(k)] * P^T[pi(k)][q]; V LDS sigma-permuted to match pi
    __builtin_amdgcn_s_setprio(1);
#pragma unroll
    for (int dsub = 0; dsub < 8; ++dsub) {
      bf16x8 vf = *(const bf16x8*)(sV + (dsub * 16 + l15) * 64 +
                                   ((g * 16) ^ ((l15 & 3) << 4)));
      o[0][dsub] = __builtin_amdgcn_mfma_f32_16x16x32_bf16(vf, pf[0].v, o[0][dsub], 0, 0, 0);
      o[1][dsub] = __builtin_amdgcn_mfma_f32_16x16x32_bf16(vf, pf[1].v, o[1][dsub], 0, 0, 0);
    }
    __builtin_amdgcn_s_setprio(0);
    cb = (cb == 2) ? 0 : cb + 1;
  }

#pragma unroll
  for (int h = 0; h < 2; ++h) {
    lsum[h] += __shfl_xor(lsum[h], 16);
    lsum[h] += __shfl_xor(lsum[h], 32);
    int ridx = (b * 16 + j) * 128 + w * 32 + h * 16 + l15;  // global q row
    u16* dst = po + ((size_t)sp * NROWS + ridx) * 128;
#pragma unroll
    for (int dsub = 0; dsub < 8; ++dsub) {
      union { uint32_t u[2]; u16x4 v; } pk2;
      pk2.u[0] = cvtpk(o[h][dsub][0], o[h][dsub][1]);
      pk2.u[1] = cvtpk(o[h][dsub][2], o[h][dsub][3]);
      *(u16x4*)(dst + dsub * 16 + g * 4) = pk2.v;  // unnormalized bf16 partial
    }
    if (g == 0) ls[(size_t)sp * NROWS + ridx] = lsum[h];
  }
}

// ---------------- Kernel 3: combine KV-split partials (shared m=0 -> sum/sum) ---------
__global__ __launch_bounds__(256) void attn_combine(const u16* __restrict__ po,
                                                    const float* __restrict__ ls,
                                                    float* __restrict__ out) {
  int idx = blockIdx.x * 256 + threadIdx.x;  // 16384 rows * 16 d-chunks
  int r = idx >> 4, d0 = (idx & 15) * 8;
  float denom = 0.f;
  float acc[8];
#pragma unroll
  for (int j = 0; j < 8; ++j) acc[j] = 0.f;
#pragma unroll
  for (int s = 0; s < NSPLIT; ++s) {
    denom += ls[(size_t)s * NROWS + r];
    bf16x8 v = *(const bf16x8*)(po + ((size_t)s * NROWS + r) * 128 + d0);
#pragma unroll
    for (int j = 0; j < 8; ++j) {
      uint32_t bits = ((uint32_t)(u16)v[j]) << 16;
      acc[j] += *reinterpret_cast<float*>(&bits);
    }
  }
  float inv = 1.0f / denom;
  f32x4 o0 = (f32x4){acc[0], acc[1], acc[2], acc[3]};
  f32x4 o1 = (f32x4){acc[4], acc[5], acc[6], acc[7]};
  *(f32x4*)(out + (size_t)r * 128 + d0) = o0 * inv;
  *(f32x4*)(out + (size_t)r * 128 + d0 + 4) = o1 * inv;
}

extern "C" void kernel_launch(void* const* d_in, const int* in_sizes, int n_in,
                              void* d_out, int out_size, void* d_ws, size_t ws_size,
                              hipStream_t stream) {
  const float* x = (const float*)d_in[0];
  const float* wq = (const float*)d_in[2];
  const float* wk = (const float*)d_in[3];
  const float* wv = (const float*)d_in[4];

  char* ws = (char*)d_ws;
  u16* po = (u16*)ws;                        // [4][16384][128] bf16 = 16,777,216 B
  float* ls = (float*)(ws + 16777216);       // [4][16384] f32 = 262,144 B
  u16* wt3 = (u16*)(ws + 17039360);          // 786,432 B (BK=64-tile-major, pre-swizzled)
  u16* qb = (u16*)(ws + 17825792);           // 4,194,304 B
  u16* kb = (u16*)(ws + 22020096);           // 4,194,304 B
  u16* vt = (u16*)(ws + 26214400);           // 4,194,304 B (transposed, sigma-permuted)
  float* out = (float*)d_out;

  wcvt<<<dim3(1536), dim3(256), 0, stream>>>(wq, wk, wv, wt3);
  qkv_gemm<<<dim3(256), dim3(512), 0, stream>>>(x, wt3, qb, kb, vt);
  attn<<<dim3(512), dim3(256), 0, stream>>>(qb, kb, vt, po, ls);
  attn_combine<<<dim3(1024), dim3(256), 0, stream>>>(po, ls, out);
}

// Round 16
// 59.338 us; speedup vs baseline: 1.6186x; 1.6186x over previous
//
#include <hip/hip_runtime.h>
#include <hip/hip_bf16.h>
#include <stdint.h>

typedef __attribute__((ext_vector_type(8))) short bf16x8;
typedef __attribute__((ext_vector_type(4))) float f32x4;
typedef __attribute__((ext_vector_type(4))) unsigned short u16x4;
typedef unsigned short u16;

#define D_MODEL 1024
#define DK 128
#define BATCH 8
#define SEQ 2048
#define NROWS (BATCH * SEQ) /* 16384 */
#define NSPLIT 4
#define KVPB 512  /* KV rows per block */
#define NIT 16    /* KVPB / 32 */

static __device__ __forceinline__ void gl_lds16(const void* g, void* l) {
  __builtin_amdgcn_global_load_lds((const __attribute__((address_space(1))) void*)g,
                                   (__attribute__((address_space(3))) void*)l, 16, 0, 0);
}

static __device__ __forceinline__ u16 f2b(float f) {
  __hip_bfloat16 h = __float2bfloat16(f);
  return *reinterpret_cast<u16*>(&h);
}

static __device__ __forceinline__ uint32_t cvtpk(float lo, float hi) {
  uint32_t r;
  asm("v_cvt_pk_bf16_f32 %0, %1, %2" : "=v"(r) : "v"(lo), "v"(hi));
  return r;
}

static __device__ __forceinline__ float exp2hw(float x) {
  float r;
  asm("v_exp_f32 %0, %1" : "=v"(r) : "v"(x));
  return r;
}

// ---------------- Kernel 0: W -> bf16, K-tile-major pre-swizzled layout ---------------
// wt2[kt][np][slot] : kt=k>>5 (32 K-tiles), np = w*128+n (0..383),
// slot = ((k>>3)&3) ^ ((np>>1)&3)  (granule-XOR swizzle PRE-APPLIED), elem = k&7.
__global__ __launch_bounds__(256) void wcvt(const float* __restrict__ wq,
                                            const float* __restrict__ wk,
                                            const float* __restrict__ wv,
                                            u16* __restrict__ wt2) {
  const int idx = blockIdx.x * 256 + threadIdx.x;  // exactly 393216
  int w = idx >> 17, rr = idx & 131071, k = rr >> 7, n = rr & 127;
  const float* W = (w == 0) ? wq : ((w == 1) ? wk : wv);
  int np = w * 128 + n;
  int kt = k >> 5;
  int slot = ((k >> 3) & 3) ^ ((np >> 1) & 3);
  size_t dst = ((size_t)kt * 1536 + np * 4 + slot) * 8 + (k & 7);
  wt2[dst] = f2b(W[k * DK + n]);
}

// ---------------- Kernel 1: fused cvt+GEMM (R13 best-measured config, unchanged) ------
__global__ __launch_bounds__(256, 2) void qkv_gemm(const float* __restrict__ x,
                                                   const u16* __restrict__ wt2,
                                                   u16* __restrict__ qb,
                                                   u16* __restrict__ kb,
                                                   u16* __restrict__ vt) {
  __shared__ char sm[61440] __attribute__((aligned(16)));  // 3 bufs x (A-f32 8K + B 12K)
  const int tid = threadIdx.x;        // 0..255
  const int lane = tid & 63;
  const int w = tid >> 6;             // 0..3
  const int g = lane >> 4;            // 0..3
  const int l15 = lane & 15;
  const int id = blockIdx.x;
  const int wgid = ((id & 7) << 6) | (id >> 3);
  const int panel = wgid >> 1;        // 0..255 (64-row panel)
  const int half = wgid & 1;          // 0..1 (cols 0-191 | 192-383)
  const int wm = w >> 1, wn = w & 1;

  const char* aB = (const char*)x + (size_t)panel * 64 * 4096;  // f32 row stride 4096 B
  const char* bB = (const char*)wt2 + half * 12288;

  f32x4 acc[2][6];
#pragma unroll
  for (int i = 0; i < 2; ++i)
#pragma unroll
    for (int jj = 0; jj < 6; ++jj) acc[i][jj] = (f32x4){0.f, 0.f, 0.f, 0.f};

  auto stage = [&](int buf, int kt) {
    char* sA = sm + buf * 20480;
    char* sB = sA + 8192;
#pragma unroll
    for (int c = 0; c < 2; ++c) {
      int gi = c * 256 + tid;                        // 0..511 granule-slots
      int row = gi >> 3;
      int gq = (gi & 7) ^ (row & 7);                 // inverse-swizzled source granule
      gl_lds16(aB + (size_t)row * 4096 + kt * 128 + (gq << 4), sA + c * 4096 + w * 1024);
    }
    const char* bSrc = bB + (size_t)kt * 24576;
#pragma unroll
    for (int c = 0; c < 3; ++c) {
      gl_lds16(bSrc + (c * 256 + tid) * 16, sB + c * 4096 + w * 1024);  // linear
    }
  };

  auto compute = [&](const char* base) {
    const char* sA = base;
    const char* sB = base + 8192;
    bf16x8 af[2];
#pragma unroll
    for (int mi = 0; mi < 2; ++mi) {
      int row = wm * 32 + mi * 16 + l15;
      f32x4 lo = *(const f32x4*)(sA + row * 128 + ((((2 * g + 0) ^ (row & 7))) << 4));
      f32x4 hi = *(const f32x4*)(sA + row * 128 + ((((2 * g + 1) ^ (row & 7))) << 4));
      union { uint32_t u[4]; bf16x8 v; } tt;
      tt.u[0] = cvtpk(lo[0], lo[1]);
      tt.u[1] = cvtpk(lo[2], lo[3]);
      tt.u[2] = cvtpk(hi[0], hi[1]);
      tt.u[3] = cvtpk(hi[2], hi[3]);
      af[mi] = tt.v;
    }
    bf16x8 bfr[6];
#pragma unroll
    for (int ni = 0; ni < 6; ++ni) {
      int npl = wn * 96 + ni * 16 + l15;
      bfr[ni] = *(const bf16x8*)(sB + npl * 64 + ((g ^ ((npl >> 1) & 3)) << 4));
    }
    __builtin_amdgcn_s_setprio(1);
#pragma unroll
    for (int mi = 0; mi < 2; ++mi)
#pragma unroll
      for (int ni = 0; ni < 6; ++ni)
        acc[mi][ni] = __builtin_amdgcn_mfma_f32_16x16x32_bf16(af[mi], bfr[ni], acc[mi][ni], 0, 0, 0);
    __builtin_amdgcn_s_setprio(0);
  };

  stage(0, 0);
  stage(1, 1);
  int cb = 0;
#pragma unroll 1
  for (int t = 0; t < 32; ++t) {
    if (t < 31) asm volatile("s_waitcnt vmcnt(5)" ::: "memory");
    else asm volatile("s_waitcnt vmcnt(0)" ::: "memory");
    __builtin_amdgcn_s_barrier();
    if (t + 2 < 32) {
      int sb = cb + 2;
      if (sb >= 3) sb -= 3;
      stage(sb, t + 2);
    }
    compute(sm + cb * 20480);
    cb = (cb == 2) ? 0 : cb + 1;
  }

  // qscale = (1/sqrt(128)) * log2(e): softmax done as exp2 with no max subtraction
  const float qscale = 0.12751743f;
#pragma unroll
  for (int mi = 0; mi < 2; ++mi) {
#pragma unroll
    for (int ni = 0; ni < 6; ++ni) {
      int mbase = panel * 64 + wm * 32 + mi * 16 + g * 4;
      int np = half * 192 + wn * 96 + ni * 16 + l15;
      int ntd = np >> 7, n = np & 127;
      if (ntd == 2) {
        int b = mbase >> 11, s = mbase & 2047;
        int a = (s >> 2) & 7;
        int sp2 = (s & ~31) | ((((a & 3) << 1) | (a >> 2)) << 2);
        union { u16 u[4]; u16x4 v; } pk;
#pragma unroll
        for (int r2 = 0; r2 < 4; ++r2) pk.u[r2] = f2b(acc[mi][ni][r2]);
        *(u16x4*)((char*)vt + ((size_t)(b * 128 + n) * 2048 + sp2) * 2) = pk.v;
      } else {
        u16* dst = (ntd == 0) ? qb : kb;
        float sc = (ntd == 0) ? qscale : 1.0f;
#pragma unroll
        for (int r2 = 0; r2 < 4; ++r2)
          dst[(size_t)(mbase + r2) * 128 + n] = f2b(acc[mi][ni][r2] * sc);
      }
    }
  }
}

// ---------------- Kernel 2: flash attention partial, 8 waves x 32 q = 256 q/block -----
// Halves K/V re-staging (134 -> 67 MB): 256 blocks, each covers 256 q rows with the
// SAME per-wave structure as before. Stage = 1 K + 1 V gl_lds per thread (512 thr).
// Q pre-scaled bf16 [b][s][128]; K bf16 [b][s][128]; V^T bf16 [b][d][s] sigma-permuted.
__global__ __launch_bounds__(512) void attn(const u16* __restrict__ qb,
                                            const u16* __restrict__ kb,
                                            const u16* __restrict__ vtg,
                                            u16* __restrict__ po,
                                            float* __restrict__ ls) {
  __shared__ char sm[49152] __attribute__((aligned(16)));  // K 3x8K | V 3x8K
  const int tid = threadIdx.x, lane = tid & 63, w = tid >> 6;  // 8 waves
  const int g = lane >> 4, l15 = lane & 15;
  // XCD swizzle (256 blocks): batch b's 32 blocks (4 splits x 8 q-tiles) on one XCD
  const int id = blockIdx.x;  // 0..255
  const int wgid = ((id & 7) << 5) | (id >> 3);
  const int b = wgid >> 5, sp = (wgid >> 3) & 3, jj = wgid & 7;
  const int s0q = jj * 256 + w * 32;  // this wave's first q row within batch
  const int kv0 = sp * KVPB;

  const char* qB = (const char*)qb + (size_t)b * SEQ * 256;
  const char* kB = (const char*)kb + (size_t)b * SEQ * 256;
  const char* vB = (const char*)vtg + (size_t)b * 128 * SEQ * 2;

  // Q fragments first (oldest in vmcnt queue): lane holds Q[q=l15][d=kk*32+g*8..+7]
  bf16x8 qf[2][4];
#pragma unroll
  for (int h = 0; h < 2; ++h)
#pragma unroll
    for (int kk = 0; kk < 4; ++kk)
      qf[h][kk] = *(const bf16x8*)(qB + (size_t)(s0q + h * 16 + l15) * 256 + kk * 64 + g * 16);

  f32x4 o[2][8];
#pragma unroll
  for (int h = 0; h < 2; ++h)
#pragma unroll
    for (int i = 0; i < 8; ++i) o[h][i] = (f32x4){0.f, 0.f, 0.f, 0.f};
  float lsum[2] = {0.f, 0.f};

  char* sKb = sm;          // [3][8192] K tile [32 kv][256 B], swizzled
  char* sVb = sm + 24576;  // [3][8192] V^T tile [128 d][64 B], swizzled+sigma-permuted

  // 512 threads: one K + one V gl_lds per thread covers the full 8 KB tiles
  auto stage = [&](int bi, int it) {
    char* sK = sKb + bi * 8192;
    char* sV = sVb + bi * 8192;
    int s0 = kv0 + it * 32;
    int base = w * 1024;             // wave-uniform LDS dest, w 0..7 -> 8 KB
    int L = base + lane * 16;
    {
      int row = L >> 8, col = L & 255;
      gl_lds16(kB + (size_t)(s0 + row) * 256 + (col ^ ((row & 7) << 4)), sK + base);
    }
    {
      int rv = L >> 6, cv = L & 63;
      gl_lds16(vB + (size_t)rv * 4096 + (size_t)s0 * 2 + (cv ^ ((rv & 3) << 4)), sV + base);
    }
  };

  stage(0, 0);
  stage(1, 1);
  int cb = 0;
  for (int t = 0; t < NIT; ++t) {
    if (t < NIT - 1) asm volatile("s_waitcnt vmcnt(2)" ::: "memory");
    else asm volatile("s_waitcnt vmcnt(0)" ::: "memory");
    __builtin_amdgcn_s_barrier();
    if (t + 2 < NIT) {
      int sb = cb + 2;
      if (sb >= 3) sb -= 3;
      stage(sb, t + 2);  // writes buf (t+2)%3: disjoint from all live readers
    }
    const char* sK = sKb + cb * 8192;
    const char* sV = sVb + cb * 8192;

    // QK^T (swapped): S^T[kv][q]; A = K fragment (shared across groups), B = Q fragment
    f32x4 st[2][2];
    st[0][0] = (f32x4){0.f, 0.f, 0.f, 0.f}; st[0][1] = st[0][0];
    st[1][0] = st[0][0]; st[1][1] = st[0][0];
    __builtin_amdgcn_s_setprio(1);
#pragma unroll
    for (int sub = 0; sub < 2; ++sub)
#pragma unroll
      for (int kk = 0; kk < 4; ++kk) {
        bf16x8 kf = *(const bf16x8*)(sK + (sub * 16 + l15) * 256 +
                                     ((kk * 64 + g * 16) ^ ((l15 & 7) << 4)));
        st[0][sub] = __builtin_amdgcn_mfma_f32_16x16x32_bf16(kf, qf[0][kk], st[0][sub], 0, 0, 0);
        st[1][sub] = __builtin_amdgcn_mfma_f32_16x16x32_bf16(kf, qf[1][kk], st[1][sub], 0, 0, 0);
      }
    __builtin_amdgcn_s_setprio(0);

    // m=0 softmax: p = exp2(st) (Q pre-scaled by log2e/sqrt(d)); pack in-register.
    // k-slot permutation pi(g*8+j) = g*4+j | 16+g*4+(j-4): B-operand is lane-local.
    union U { uint32_t u[4]; bf16x8 v; } pf[2];
#pragma unroll
    for (int h = 0; h < 2; ++h) {
      float p[8];
#pragma unroll
      for (int sub = 0; sub < 2; ++sub)
#pragma unroll
        for (int r2 = 0; r2 < 4; ++r2) {
          float e = exp2hw(st[h][sub][r2]);
          lsum[h] += e;
          p[sub * 4 + r2] = e;
        }
      pf[h].u[0] = cvtpk(p[0], p[1]);
      pf[h].u[1] = cvtpk(p[2], p[3]);
      pf[h].u[2] = cvtpk(p[4], p[5]);
      pf[h].u[3] = cvtpk(p[6], p[7]);
    }

    // PV: O^T[d][q] += V^T[d][pi(k)] * P^T[pi(k)][q]; V LDS sigma-permuted to match pi
    __builtin_amdgcn_s_setprio(1);
#pragma unroll
    for (int dsub = 0; dsub < 8; ++dsub) {
      bf16x8 vf = *(const bf16x8*)(sV + (dsub * 16 + l15) * 64 +
                                   ((g * 16) ^ ((l15 & 3) << 4)));
      o[0][dsub] = __builtin_amdgcn_mfma_f32_16x16x32_bf16(vf, pf[0].v, o[0][dsub], 0, 0, 0);
      o[1][dsub] = __builtin_amdgcn_mfma_f32_16x16x32_bf16(vf, pf[1].v, o[1][dsub], 0, 0, 0);
    }
    __builtin_amdgcn_s_setprio(0);
    cb = (cb == 2) ? 0 : cb + 1;
  }

#pragma unroll
  for (int h = 0; h < 2; ++h) {
    lsum[h] += __shfl_xor(lsum[h], 16);
    lsum[h] += __shfl_xor(lsum[h], 32);
    int ridx = b * 2048 + jj * 256 + w * 32 + h * 16 + l15;  // global q row
    u16* dst = po + ((size_t)sp * NROWS + ridx) * 128;
#pragma unroll
    for (int dsub = 0; dsub < 8; ++dsub) {
      union { uint32_t u[2]; u16x4 v; } pk2;
      pk2.u[0] = cvtpk(o[h][dsub][0], o[h][dsub][1]);
      pk2.u[1] = cvtpk(o[h][dsub][2], o[h][dsub][3]);
      *(u16x4*)(dst + dsub * 16 + g * 4) = pk2.v;  // unnormalized bf16 partial
    }
    if (g == 0) ls[(size_t)sp * NROWS + ridx] = lsum[h];
  }
}

// ---------------- Kernel 3: combine KV-split partials (shared m=0 -> sum/sum) ---------
__global__ __launch_bounds__(256) void attn_combine(const u16* __restrict__ po,
                                                    const float* __restrict__ ls,
                                                    float* __restrict__ out) {
  int idx = blockIdx.x * 256 + threadIdx.x;  // 16384 rows * 16 d-chunks
  int r = idx >> 4, d0 = (idx & 15) * 8;
  float denom = 0.f;
  float acc[8];
#pragma unroll
  for (int j = 0; j < 8; ++j) acc[j] = 0.f;
#pragma unroll
  for (int s = 0; s < NSPLIT; ++s) {
    denom += ls[(size_t)s * NROWS + r];
    bf16x8 v = *(const bf16x8*)(po + ((size_t)s * NROWS + r) * 128 + d0);
#pragma unroll
    for (int j = 0; j < 8; ++j) {
      uint32_t bits = ((uint32_t)(u16)v[j]) << 16;
      acc[j] += *reinterpret_cast<float*>(&bits);
    }
  }
  float inv = 1.0f / denom;
  f32x4 o0 = (f32x4){acc[0], acc[1], acc[2], acc[3]};
  f32x4 o1 = (f32x4){acc[4], acc[5], acc[6], acc[7]};
  *(f32x4*)(out + (size_t)r * 128 + d0) = o0 * inv;
  *(f32x4*)(out + (size_t)r * 128 + d0 + 4) = o1 * inv;
}

extern "C" void kernel_launch(void* const* d_in, const int* in_sizes, int n_in,
                              void* d_out, int out_size, void* d_ws, size_t ws_size,
                              hipStream_t stream) {
  const float* x = (const float*)d_in[0];
  const float* wq = (const float*)d_in[2];
  const float* wk = (const float*)d_in[3];
  const float* wv = (const float*)d_in[4];

  char* ws = (char*)d_ws;
  u16* po = (u16*)ws;                        // [4][16384][128] bf16 = 16,777,216 B
  float* ls = (float*)(ws + 16777216);       // [4][16384] f32 = 262,144 B
  u16* wt2 = (u16*)(ws + 17039360);          // 786,432 B (K-tile-major, pre-swizzled)
  u16* qb = (u16*)(ws + 17825792);           // 4,194,304 B
  u16* kb = (u16*)(ws + 22020096);           // 4,194,304 B
  u16* vt = (u16*)(ws + 26214400);           // 4,194,304 B (transposed, sigma-permuted)
  float* out = (float*)d_out;

  wcvt<<<dim3(1536), dim3(256), 0, stream>>>(wq, wk, wv, wt2);
  qkv_gemm<<<dim3(512), dim3(256), 0, stream>>>(x, wt2, qb, kb, vt);
  attn<<<dim3(256), dim3(512), 0, stream>>>(qb, kb, vt, po, ls);
  attn_combine<<<dim3(1024), dim3(256), 0, stream>>>(po, ls, out);
}